// Round 1
// baseline (391.349 us; speedup 1.0000x reference)
//
#include <hip/hip_runtime.h>
#include <hip/hip_bf16.h>
#include <cstdint>
#include <cstddef>

// Problem: B=64, L=2048, E=1024, A=512
#define BB   64
#define LL   2048
#define ED   1024
#define AD   512
#define BM   128          // l-rows per block
#define BK   32           // K per MFMA step
#define NCH  (LL / BM)    // 16 chunks per batch row
#define KST  (ED / BK)    // 32 K-steps

typedef short  short8  __attribute__((ext_vector_type(8)));
typedef float  f32x4   __attribute__((ext_vector_type(4)));

__device__ __forceinline__ unsigned short f2bf(float x) {
  // round-to-nearest-even fp32 -> bf16
  unsigned u = __float_as_uint(x);
  u += 0x7FFFu + ((u >> 16) & 1u);
  return (unsigned short)(u >> 16);
}

// ---------------- kernel 0: prep ----------------
// blocks 0..127  : dec_proj = dec @ W_dec + b_dec  -> dp [64][512] (fp32, exact)
// blocks 128..255: pack W_enc fp32 -> bf16 in MFMA-B layout Wb[kg][n][j], k=kg*8+j
__global__ __launch_bounds__(256) void prep_kernel(
    const float* __restrict__ W_enc, const float* __restrict__ dec,
    const float* __restrict__ W_dec, const float* __restrict__ b_dec,
    unsigned short* __restrict__ Wb, float* __restrict__ dp) {
  const int blk = blockIdx.x, t = threadIdx.x;
  if (blk < 128) {
    const int b = blk >> 1;
    const int c = (blk & 1) * 256 + t;
    float a = 0.f;
#pragma unroll 4
    for (int k = 0; k < ED; k++)
      a = fmaf(dec[b * ED + k], W_dec[k * AD + c], a);
    dp[b * AD + c] = a + b_dec[c];
  } else {
    const int base = (blk - 128) * 4096;
#pragma unroll
    for (int i = 0; i < 16; i++) {
      const int idx = base + i * 256 + t;
      const int k = idx >> 9, n = idx & 511;
      Wb[((k >> 3) * AD + n) * 8 + (k & 7)] = f2bf(W_enc[idx]);
    }
  }
}

// ---------------- kernel 1: fused GEMM + tanh-score + online-softmax partials ----
// grid (NCH, BB), 512 threads = 8 waves as 2M x 4N, wave tile 64 rows x 128 cols.
// A (sem) fp32->bf16 staged via regs; B (Wb) bf16 staged via regs. Single LDS buffer,
// next-step global loads issued before MFMAs (latency hidden), written after barrier.
__global__ __launch_bounds__(512, 2) void fused_kernel(
    const float* __restrict__ sem, const unsigned short* __restrict__ Wb,
    const float* __restrict__ dp, const float* __restrict__ b_enc,
    const float* __restrict__ Wf,
    float* __restrict__ raw_scores,     // d_out + 64*512, holds raw scores pre-normalize
    float* __restrict__ ws_ms, float* __restrict__ ws_o) {

  // A packed [kg][row][8], kg stride 1040 elems (pad 8) to spread banks
  __shared__ unsigned short Alds[4 * 1040];       //  8320 B
  __shared__ unsigned short Blds[4 * AD * 8];     // 32768 B
  __shared__ float sc_part[BM][4];
  __shared__ float scores_lds[BM];
  __shared__ float weight[BM];
  __shared__ float o_lds[2][AD];
  __shared__ float bc[2];                          // m_c, s_c broadcast

  const int t    = threadIdx.x;
  const int lane = t & 63;
  const int wave = t >> 6;
  const int wm   = wave >> 2;   // 0..1 (row half)
  const int wn   = wave & 3;    // 0..3 (col quarter)
  const int b    = blockIdx.y;
  const int chunk= blockIdx.x;
  const int l0   = chunk * BM;

  // staging mapping: thread -> (row, kg)
  const int srow = t >> 2;      // 0..127
  const int skg  = t & 3;       // 0..3
  const float* aptr = sem + ((size_t)(b * LL + l0 + srow)) * ED + skg * 8;
  const unsigned short* bsrc = Wb + t * 8;   // + ks*16384 + i*4096

  // frag addressing
  const int arow  = lane & 15;
  const int akg   = lane >> 4;
  const int abase = akg * 1040 + (wm * 64 + arow) * 8;     // + mf*128
  const int bbase = akg * (AD * 8) + (wn * 128 + arow) * 8; // + nf*128

  f32x4 acc[4][8];
#pragma unroll
  for (int i = 0; i < 4; i++)
#pragma unroll
    for (int j = 0; j < 8; j++) acc[i][j] = (f32x4)0.f;

  // ---- stage K-step 0 ----
  {
    f32x4 f0 = *(const f32x4*)(aptr);
    f32x4 f1 = *(const f32x4*)(aptr + 4);
    short8 bv0 = *(const short8*)(bsrc);
    short8 bv1 = *(const short8*)(bsrc + 4096);
    short8 bv2 = *(const short8*)(bsrc + 8192);
    short8 bv3 = *(const short8*)(bsrc + 12288);
    short8 av;
    av[0]=(short)f2bf(f0[0]); av[1]=(short)f2bf(f0[1]); av[2]=(short)f2bf(f0[2]); av[3]=(short)f2bf(f0[3]);
    av[4]=(short)f2bf(f1[0]); av[5]=(short)f2bf(f1[1]); av[6]=(short)f2bf(f1[2]); av[7]=(short)f2bf(f1[3]);
    *(short8*)&Alds[skg * 1040 + srow * 8] = av;
    *(short8*)&Blds[t * 8]         = bv0;
    *(short8*)&Blds[t * 8 + 4096]  = bv1;
    *(short8*)&Blds[t * 8 + 8192]  = bv2;
    *(short8*)&Blds[t * 8 + 12288] = bv3;
  }
  __syncthreads();

  // ---- main K loop ----
  for (int ks = 0; ks < KST; ks++) {
    f32x4 nf0, nf1; short8 nb0, nb1, nb2, nb3;
    const bool more = (ks + 1 < KST);
    if (more) {  // issue next-step global loads (latency hidden under MFMAs)
      const float* ap = aptr + (ks + 1) * BK;
      nf0 = *(const f32x4*)(ap);
      nf1 = *(const f32x4*)(ap + 4);
      const unsigned short* bs = bsrc + (ks + 1) * 16384;
      nb0 = *(const short8*)(bs);
      nb1 = *(const short8*)(bs + 4096);
      nb2 = *(const short8*)(bs + 8192);
      nb3 = *(const short8*)(bs + 12288);
    }
    // compute current step
    short8 av[4], bv[8];
#pragma unroll
    for (int mf = 0; mf < 4; mf++) av[mf] = *(const short8*)&Alds[abase + mf * 128];
#pragma unroll
    for (int nf = 0; nf < 8; nf++) bv[nf] = *(const short8*)&Blds[bbase + nf * 128];
#pragma unroll
    for (int mf = 0; mf < 4; mf++)
#pragma unroll
      for (int nf = 0; nf < 8; nf++)
        acc[mf][nf] = __builtin_amdgcn_mfma_f32_16x16x32_bf16(av[mf], bv[nf], acc[mf][nf], 0, 0, 0);
    __syncthreads();   // all frag reads done before overwrite
    if (more) {
      short8 aw;
      aw[0]=(short)f2bf(nf0[0]); aw[1]=(short)f2bf(nf0[1]); aw[2]=(short)f2bf(nf0[2]); aw[3]=(short)f2bf(nf0[3]);
      aw[4]=(short)f2bf(nf1[0]); aw[5]=(short)f2bf(nf1[1]); aw[6]=(short)f2bf(nf1[2]); aw[7]=(short)f2bf(nf1[3]);
      *(short8*)&Alds[skg * 1040 + srow * 8] = aw;
      *(short8*)&Blds[t * 8]         = nb0;
      *(short8*)&Blds[t * 8 + 4096]  = nb1;
      *(short8*)&Blds[t * 8 + 8192]  = nb2;
      *(short8*)&Blds[t * 8 + 12288] = nb3;
    }
    __syncthreads();
  }

  // ---- epilogue: add b_enc, tanh-score, online-softmax partials ----
  float dpv[8], wfv[8], bev[8];
#pragma unroll
  for (int nf = 0; nf < 8; nf++) {
    const int c = wn * 128 + nf * 16 + arow;
    dpv[nf] = dp[b * AD + c];
    wfv[nf] = Wf[c];
    bev[nf] = b_enc[c];
  }
#pragma unroll
  for (int mf = 0; mf < 4; mf++) {
#pragma unroll
    for (int r = 0; r < 4; r++) {
      float p = 0.f;
#pragma unroll
      for (int nf = 0; nf < 8; nf++) {
        float e = acc[mf][nf][r] + bev[nf];
        acc[mf][nf][r] = e;                      // enc_proj incl. b_enc (kept for o-accum)
        float x = e + dpv[nf];
        float ex = __expf(2.f * x);              // tanh via exp
        float th = 1.f - 2.f / (ex + 1.f);
        p = fmaf(th, wfv[nf], p);
      }
      p += __shfl_xor(p, 1); p += __shfl_xor(p, 2);
      p += __shfl_xor(p, 4); p += __shfl_xor(p, 8);
      if (arow == 0) sc_part[wm * 64 + mf * 16 + akg * 4 + r][wn] = p;
    }
  }
  __syncthreads();

  if (t < BM) {
    float s = sc_part[t][0] + sc_part[t][1] + sc_part[t][2] + sc_part[t][3];
    scores_lds[t] = s;
    raw_scores[(size_t)b * LL + l0 + t] = s;     // raw; finalize normalizes in place
  }
  __syncthreads();
  if (t < 64) {
    float m = fmaxf(scores_lds[t], scores_lds[t + 64]);
#pragma unroll
    for (int off = 1; off < 64; off <<= 1) m = fmaxf(m, __shfl_xor(m, off));
    if (t == 0) bc[0] = m;
  }
  __syncthreads();
  const float m_c = bc[0];
  if (t < BM) weight[t] = __expf(scores_lds[t] - m_c);
  __syncthreads();
  if (t < 64) {
    float s = weight[t] + weight[t + 64];
#pragma unroll
    for (int off = 1; off < 64; off <<= 1) s += __shfl_xor(s, off);
    if (t == 0) bc[1] = s;
  }

  float wv[4][4];
#pragma unroll
  for (int mf = 0; mf < 4; mf++)
#pragma unroll
    for (int r = 0; r < 4; r++) wv[mf][r] = weight[wm * 64 + mf * 16 + akg * 4 + r];
#pragma unroll
  for (int nf = 0; nf < 8; nf++) {
    float cp = 0.f;
#pragma unroll
    for (int mf = 0; mf < 4; mf++)
#pragma unroll
      for (int r = 0; r < 4; r++) cp = fmaf(wv[mf][r], acc[mf][nf][r], cp);
    cp += __shfl_xor(cp, 16);
    cp += __shfl_xor(cp, 32);
    if (lane < 16) o_lds[wm][wn * 128 + nf * 16 + lane] = cp;
  }
  __syncthreads();
  if (t < AD)
    ws_o[((size_t)b * NCH + chunk) * AD + t] = o_lds[0][t] + o_lds[1][t];
  if (t == 0) {
    ws_ms[(b * NCH + chunk) * 2]     = m_c;
    ws_ms[(b * NCH + chunk) * 2 + 1] = bc[1];
  }
}

// ---------------- kernel 2: finalize (merge chunk partials, normalize) ----------
__global__ __launch_bounds__(256) void finalize_kernel(
    const float* __restrict__ ws_ms, const float* __restrict__ ws_o,
    float* __restrict__ out0, float* __restrict__ outS) {
  const int b = blockIdx.x, t = threadIdx.x;
  float ms[NCH], ss[NCH];
  float M = -1e30f;
#pragma unroll
  for (int i = 0; i < NCH; i++) {
    ms[i] = ws_ms[(b * NCH + i) * 2];
    ss[i] = ws_ms[(b * NCH + i) * 2 + 1];
    M = fmaxf(M, ms[i]);
  }
  float S = 0.f, w[NCH];
#pragma unroll
  for (int i = 0; i < NCH; i++) { w[i] = __expf(ms[i] - M); S = fmaf(ss[i], w[i], S); }
  const float invS = 1.f / S;
  for (int c = t; c < AD; c += 256) {
    float a = 0.f;
#pragma unroll
    for (int i = 0; i < NCH; i++) a = fmaf(ws_o[((size_t)b * NCH + i) * AD + c], w[i], a);
    out0[b * AD + c] = a * invS;
  }
  for (int l = t; l < LL; l += 256) {
    float r = outS[(size_t)b * LL + l];
    outS[(size_t)b * LL + l] = __expf(r - M) * invS;
  }
}

extern "C" void kernel_launch(void* const* d_in, const int* in_sizes, int n_in,
                              void* d_out, int out_size, void* d_ws, size_t ws_size,
                              hipStream_t stream) {
  const float* sem    = (const float*)d_in[0];
  const float* dec    = (const float*)d_in[1];
  const float* W_enc  = (const float*)d_in[2];
  const float* b_enc  = (const float*)d_in[3];
  const float* W_dec  = (const float*)d_in[4];
  const float* b_dec  = (const float*)d_in[5];
  const float* W_full = (const float*)d_in[6];
  // d_in[7] = b_full: constant shift, cancels in softmax; never output raw scores.

  float* out0 = (float*)d_out;            // att_output [64][512]
  float* outS = out0 + BB * AD;           // att_scores [64][2048]

  char* ws = (char*)d_ws;
  unsigned short* Wb = (unsigned short*)ws;                          // 1 MB bf16 packed W_enc
  float* dpw   = (float*)(ws + (1 << 20));                           // 128 KB dec_proj+b_dec
  float* ws_ms = (float*)(ws + (1 << 20) + (128 << 10));             // 8 KB (m,s) per chunk
  float* ws_o  = (float*)(ws + (1 << 20) + (128 << 10) + (8 << 10)); // 2 MB o partials

  prep_kernel<<<256, 256, 0, stream>>>(W_enc, dec, W_dec, b_dec, Wb, dpw);
  dim3 g1(NCH, BB);
  fused_kernel<<<g1, 512, 0, stream>>>(sem, Wb, dpw, b_enc, W_full, outS, ws_ms, ws_o);
  finalize_kernel<<<BB, 256, 0, stream>>>(ws_ms, ws_o, out0, outS);
}

// Round 2
// 287.143 us; speedup vs baseline: 1.3629x; 1.3629x over previous
//
#include <hip/hip_runtime.h>
#include <hip/hip_bf16.h>
#include <cstdint>
#include <cstddef>

// Problem: B=64, L=2048, E=1024, A=512
#define BB   64
#define LL   2048
#define ED   1024
#define AD   512
#define BM   128          // l-rows per block
#define BK   32           // K per step
#define NCH  (LL / BM)    // 16 chunks per batch row
#define KST  (ED / BK)    // 32 K-steps

typedef short  short8  __attribute__((ext_vector_type(8)));
typedef float  f32x4   __attribute__((ext_vector_type(4)));

__device__ __forceinline__ unsigned short f2bf(float x) {
  // round-to-nearest-even fp32 -> bf16
  unsigned u = __float_as_uint(x);
  u += 0x7FFFu + ((u >> 16) & 1u);
  return (unsigned short)(u >> 16);
}

// async global->LDS DMA, 16 bytes per thread (wave-uniform LDS base + lane*16)
#define GLOAD_LDS16(gp, lp)                                                        \
  __builtin_amdgcn_global_load_lds(                                                \
      (const __attribute__((address_space(1))) unsigned int*)(gp),                 \
      (__attribute__((address_space(3))) unsigned int*)(lp), 16, 0, 0)

// ---------------- kernel 0: prep ----------------
// blocks 0..63   : dec_proj row b = dec[b] @ W_dec + b_dec  (coalesced over cols)
// blocks 64..191 : pack W_enc fp32 -> bf16 in MFMA-B layout Wb[kg][n][j], k=kg*8+j
__global__ __launch_bounds__(512) void prep_kernel(
    const float* __restrict__ W_enc, const float* __restrict__ dec,
    const float* __restrict__ W_dec, const float* __restrict__ b_dec,
    unsigned short* __restrict__ Wb, float* __restrict__ dp) {
  const int blk = blockIdx.x, t = threadIdx.x;
  if (blk < BB) {
    const float* drow = dec + blk * ED;
    float a0 = 0.f, a1 = 0.f, a2 = 0.f, a3 = 0.f;
    for (int k = 0; k < ED; k += 4) {
      a0 = fmaf(drow[k],     W_dec[(k)     * AD + t], a0);
      a1 = fmaf(drow[k + 1], W_dec[(k + 1) * AD + t], a1);
      a2 = fmaf(drow[k + 2], W_dec[(k + 2) * AD + t], a2);
      a3 = fmaf(drow[k + 3], W_dec[(k + 3) * AD + t], a3);
    }
    dp[blk * AD + t] = (a0 + a1) + (a2 + a3) + b_dec[t];
  } else {
    const int base = (blk - BB) * 4096;
#pragma unroll
    for (int i = 0; i < 8; i++) {
      const int idx = base + i * 512 + t;
      const int k = idx >> 9, n = idx & 511;
      Wb[((k >> 3) * AD + n) * 8 + (k & 7)] = f2bf(W_enc[idx]);
    }
  }
}

// ---------------- kernel 1: fused GEMM + tanh-score + online-softmax partials ----
// grid (NCH, BB), 512 threads = 8 waves as 2M x 4N, wave tile 64 rows x 128 cols.
// 2-phase pipeline: B via async global_load_lds (double-buffered), A reg-staged
// one iteration deep (cvt+LDS-write at top of iter from regs loaded last iter).
// ONE __syncthreads per K-step; its vmcnt(0) drain only waits on loads issued a
// full iteration (~1300 cyc) earlier -> ~no stall.
__global__ __launch_bounds__(512, 2) void fused_kernel(
    const float* __restrict__ sem, const unsigned short* __restrict__ Wb,
    const float* __restrict__ dp, const float* __restrict__ b_enc,
    const float* __restrict__ Wf,
    float* __restrict__ raw_scores,
    float* __restrict__ ws_ms, float* __restrict__ ws_o) {

  __shared__ unsigned short Alds[2][4096];    // [buf][kg(4)][row(128)][8]  16 KB
  __shared__ unsigned short Blds[2][16384];   // [buf][kg(4)][col(512)][8]  64 KB

  const int t    = threadIdx.x;
  const int lane = t & 63;
  const int wave = t >> 6;
  const int wm   = wave >> 2;   // 0..1 row half
  const int wn   = wave & 3;    // 0..3 col quarter
  const int b    = blockIdx.y;
  const int chunk= blockIdx.x;
  const int l0   = chunk * BM;

  // staging mapping
  const int srow = t >> 2;      // 0..127
  const int skg  = t & 3;       // 0..3
  const float* aptr = sem + ((size_t)(b * LL + l0 + srow)) * ED + skg * 8;
  const unsigned short* bsrc = Wb + t * 8;    // + ks*16384 + i*4096
  const int awr = skg * 1024 + srow * 8;      // A LDS write offset (shorts)

  // frag addressing
  const int arow  = lane & 15;
  const int akg   = lane >> 4;
  const int abase = akg * 1024 + (wm * 64 + arow) * 8;   // + mf*128
  const int bbase = akg * 4096 + (wn * 128 + arow) * 8;  // + nf*128

  f32x4 acc[4][8];
#pragma unroll
  for (int i = 0; i < 4; i++)
#pragma unroll
    for (int j = 0; j < 8; j++) acc[i][j] = (f32x4)0.f;

  // ---- prologue: A(0)->regs->cvt->LDS0, A(1)->regs, B(0) DMA->Blds0 ----
  f32x4 pA0 = *(const f32x4*)(aptr);
  f32x4 pA1 = *(const f32x4*)(aptr + 4);
  f32x4 qA0 = *(const f32x4*)(aptr + BK);
  f32x4 qA1 = *(const f32x4*)(aptr + BK + 4);
#pragma unroll
  for (int i = 0; i < 4; i++)
    GLOAD_LDS16(bsrc + i * 4096, &Blds[0][t * 8 + i * 4096]);
  {
    short8 aw;
    aw[0]=(short)f2bf(pA0[0]); aw[1]=(short)f2bf(pA0[1]); aw[2]=(short)f2bf(pA0[2]); aw[3]=(short)f2bf(pA0[3]);
    aw[4]=(short)f2bf(pA1[0]); aw[5]=(short)f2bf(pA1[1]); aw[6]=(short)f2bf(pA1[2]); aw[7]=(short)f2bf(pA1[3]);
    *(short8*)&Alds[0][awr] = aw;
  }
  __syncthreads();

  // ---- main loop: even iters cvt qA / load pA, odd iters cvt pA / load qA ----
#define ITER(ks, CA0, CA1, LA0, LA1)                                              \
  {                                                                               \
    const int cb = (ks) & 1, nb = ((ks) + 1) & 1;                                 \
    if ((ks) + 1 < KST) {                                                         \
      short8 aw;                                                                  \
      aw[0]=(short)f2bf(CA0[0]); aw[1]=(short)f2bf(CA0[1]);                       \
      aw[2]=(short)f2bf(CA0[2]); aw[3]=(short)f2bf(CA0[3]);                       \
      aw[4]=(short)f2bf(CA1[0]); aw[5]=(short)f2bf(CA1[1]);                       \
      aw[6]=(short)f2bf(CA1[2]); aw[7]=(short)f2bf(CA1[3]);                       \
      *(short8*)&Alds[nb][awr] = aw;                                              \
    }                                                                             \
    if ((ks) + 2 < KST) {                                                         \
      const float* ap = aptr + ((ks) + 2) * BK;                                   \
      LA0 = *(const f32x4*)(ap);                                                  \
      LA1 = *(const f32x4*)(ap + 4);                                              \
    }                                                                             \
    if ((ks) + 1 < KST) {                                                         \
      const unsigned short* bs = bsrc + ((ks) + 1) * 16384;                       \
      _Pragma("unroll")                                                           \
      for (int i = 0; i < 4; i++)                                                 \
        GLOAD_LDS16(bs + i * 4096, &Blds[nb][t * 8 + i * 4096]);                  \
    }                                                                             \
    short8 av[4], bv[8];                                                          \
    _Pragma("unroll")                                                             \
    for (int mf = 0; mf < 4; mf++)                                                \
      av[mf] = *(const short8*)&Alds[cb][abase + mf * 128];                       \
    _Pragma("unroll")                                                             \
    for (int nf = 0; nf < 8; nf++)                                                \
      bv[nf] = *(const short8*)&Blds[cb][bbase + nf * 128];                       \
    _Pragma("unroll")                                                             \
    for (int mf = 0; mf < 4; mf++)                                                \
      _Pragma("unroll")                                                           \
      for (int nf = 0; nf < 8; nf++)                                              \
        acc[mf][nf] = __builtin_amdgcn_mfma_f32_16x16x32_bf16(av[mf], bv[nf], acc[mf][nf], 0, 0, 0); \
    __syncthreads();                                                              \
  }

  for (int kk = 0; kk < KST; kk += 2) {
    ITER(kk,     qA0, qA1, pA0, pA1);
    ITER(kk + 1, pA0, pA1, qA0, qA1);
  }
#undef ITER

  // ---- epilogue smem carved out of Blds (all B reads done past final barrier) --
  float* eb = (float*)&Blds[0][0];
  float (*sc_part)[4]   = (float (*)[4])eb;            // 128*4
  float* scores_lds     = eb + 512;                    // 128
  float* weight         = eb + 640;                    // 128
  float (*o_lds)[AD]    = (float (*)[AD])(eb + 768);   // 2*512
  float* bcv            = eb + 1792;                   // 2

  // ---- add b_enc, tanh-score, online-softmax partials ----
  float dpv[8], wfv[8], bev[8];
#pragma unroll
  for (int nf = 0; nf < 8; nf++) {
    const int c = wn * 128 + nf * 16 + arow;
    dpv[nf] = dp[b * AD + c];
    wfv[nf] = Wf[c];
    bev[nf] = b_enc[c];
  }
#pragma unroll
  for (int mf = 0; mf < 4; mf++) {
#pragma unroll
    for (int r = 0; r < 4; r++) {
      float p = 0.f;
#pragma unroll
      for (int nf = 0; nf < 8; nf++) {
        float e = acc[mf][nf][r] + bev[nf];
        acc[mf][nf][r] = e;                      // keep enc_proj (+b_enc) for o-accum
        float x = e + dpv[nf];
        float ex = __expf(2.f * x);              // tanh via exp
        float th = 1.f - 2.f / (ex + 1.f);
        p = fmaf(th, wfv[nf], p);
      }
      p += __shfl_xor(p, 1); p += __shfl_xor(p, 2);
      p += __shfl_xor(p, 4); p += __shfl_xor(p, 8);
      if (arow == 0) sc_part[wm * 64 + mf * 16 + akg * 4 + r][wn] = p;
    }
  }
  __syncthreads();

  if (t < BM) {
    float s = sc_part[t][0] + sc_part[t][1] + sc_part[t][2] + sc_part[t][3];
    scores_lds[t] = s;
    raw_scores[(size_t)b * LL + l0 + t] = s;     // raw; finalize normalizes in place
  }
  __syncthreads();
  if (t < 64) {
    float m = fmaxf(scores_lds[t], scores_lds[t + 64]);
#pragma unroll
    for (int off = 1; off < 64; off <<= 1) m = fmaxf(m, __shfl_xor(m, off));
    if (t == 0) bcv[0] = m;
  }
  __syncthreads();
  const float m_c = bcv[0];
  if (t < BM) weight[t] = __expf(scores_lds[t] - m_c);
  __syncthreads();
  if (t < 64) {
    float s = weight[t] + weight[t + 64];
#pragma unroll
    for (int off = 1; off < 64; off <<= 1) s += __shfl_xor(s, off);
    if (t == 0) bcv[1] = s;
  }

  float wv[4][4];
#pragma unroll
  for (int mf = 0; mf < 4; mf++)
#pragma unroll
    for (int r = 0; r < 4; r++) wv[mf][r] = weight[wm * 64 + mf * 16 + akg * 4 + r];
#pragma unroll
  for (int nf = 0; nf < 8; nf++) {
    float cp = 0.f;
#pragma unroll
    for (int mf = 0; mf < 4; mf++)
#pragma unroll
      for (int r = 0; r < 4; r++) cp = fmaf(wv[mf][r], acc[mf][nf][r], cp);
    cp += __shfl_xor(cp, 16);
    cp += __shfl_xor(cp, 32);
    if (lane < 16) o_lds[wm][wn * 128 + nf * 16 + lane] = cp;
  }
  __syncthreads();
  if (t < AD)
    ws_o[((size_t)b * NCH + chunk) * AD + t] = o_lds[0][t] + o_lds[1][t];
  if (t == 0) {
    ws_ms[(b * NCH + chunk) * 2]     = m_c;
    ws_ms[(b * NCH + chunk) * 2 + 1] = bcv[1];
  }
}

// ---------------- kernel 2: finalize (merge chunk partials, normalize) ----------
__global__ __launch_bounds__(256) void finalize_kernel(
    const float* __restrict__ ws_ms, const float* __restrict__ ws_o,
    float* __restrict__ out0, float* __restrict__ outS) {
  const int b = blockIdx.x, t = threadIdx.x;
  float ms[NCH], ss[NCH];
  float M = -1e30f;
#pragma unroll
  for (int i = 0; i < NCH; i++) {
    ms[i] = ws_ms[(b * NCH + i) * 2];
    ss[i] = ws_ms[(b * NCH + i) * 2 + 1];
    M = fmaxf(M, ms[i]);
  }
  float S = 0.f, w[NCH];
#pragma unroll
  for (int i = 0; i < NCH; i++) { w[i] = __expf(ms[i] - M); S = fmaf(ss[i], w[i], S); }
  const float invS = 1.f / S;
  for (int c = t; c < AD; c += 256) {
    float a = 0.f;
#pragma unroll
    for (int i = 0; i < NCH; i++) a = fmaf(ws_o[((size_t)b * NCH + i) * AD + c], w[i], a);
    out0[b * AD + c] = a * invS;
  }
  for (int l = t; l < LL; l += 256) {
    float r = outS[(size_t)b * LL + l];
    outS[(size_t)b * LL + l] = __expf(r - M) * invS;
  }
}

extern "C" void kernel_launch(void* const* d_in, const int* in_sizes, int n_in,
                              void* d_out, int out_size, void* d_ws, size_t ws_size,
                              hipStream_t stream) {
  const float* sem    = (const float*)d_in[0];
  const float* dec    = (const float*)d_in[1];
  const float* W_enc  = (const float*)d_in[2];
  const float* b_enc  = (const float*)d_in[3];
  const float* W_dec  = (const float*)d_in[4];
  const float* b_dec  = (const float*)d_in[5];
  const float* W_full = (const float*)d_in[6];
  // d_in[7] = b_full: constant shift, cancels in softmax.

  float* out0 = (float*)d_out;            // att_output [64][512]
  float* outS = out0 + BB * AD;           // att_scores [64][2048]

  char* ws = (char*)d_ws;
  unsigned short* Wb = (unsigned short*)ws;                          // 1 MB bf16 packed W_enc
  float* dpw   = (float*)(ws + (1 << 20));                           // 128 KB dec_proj+b_dec
  float* ws_ms = (float*)(ws + (1 << 20) + (128 << 10));             // 8 KB (m,s) per chunk
  float* ws_o  = (float*)(ws + (1 << 20) + (128 << 10) + (8 << 10)); // 2 MB o partials

  prep_kernel<<<BB + 128, 512, 0, stream>>>(W_enc, dec, W_dec, b_dec, Wb, dpw);
  dim3 g1(NCH, BB);
  fused_kernel<<<g1, 512, 0, stream>>>(sem, Wb, dpw, b_enc, W_full, outS, ws_ms, ws_o);
  finalize_kernel<<<BB, 256, 0, stream>>>(ws_ms, ws_o, out0, outS);
}